// Round 8
// baseline (325.481 us; speedup 1.0000x reference)
//
#include <hip/hip_runtime.h>
#include <math.h>

#define CCH 128
#define HH 192
#define WW 192
#define BB 2
#define HW (HH*WW)        // 36864
#define CHW (CCH*HW)      // 4718592
#define BF 128            // B * f*f = 2*64
#define NN 576            // 24*24
#define SH 24

typedef __attribute__((ext_vector_type(8))) short short8;
typedef __attribute__((ext_vector_type(4))) float floatx4;
typedef unsigned int uint32;
typedef unsigned short ushort;

__device__ __forceinline__ unsigned short bf16r(float f) {
    uint32 u = __float_as_uint(f);
    u += 0x7fffu + ((u >> 16) & 1u);
    return (unsigned short)(u >> 16);
}

// ---------------- K1: per-batch sum / sumsq reduction ----------------
__global__ __launch_bounds__(256) void k_reduce(const float* __restrict__ x, float* __restrict__ stats) {
    int b = blockIdx.y;
    const float4* p = (const float4*)(x + (size_t)b*CHW) + (size_t)blockIdx.x*4096;
    float s = 0.f, sq = 0.f;
#pragma unroll
    for (int k = 0; k < 16; ++k) {
        float4 v = p[threadIdx.x + 256*k];
        s  += v.x + v.y + v.z + v.w;
        sq += v.x*v.x + v.y*v.y + v.z*v.z + v.w*v.w;
    }
    for (int off = 32; off; off >>= 1) { s += __shfl_down(s, off); sq += __shfl_down(sq, off); }
    __shared__ float ls[4], lq[4];
    int wave = threadIdx.x >> 6, lane = threadIdx.x & 63;
    if (lane == 0) { ls[wave] = s; lq[wave] = sq; }
    __syncthreads();
    if (threadIdx.x == 0) {
        atomicAdd(&stats[2*b],   ls[0]+ls[1]+ls[2]+ls[3]);
        atomicAdd(&stats[2*b+1], lq[0]+lq[1]+lq[2]+lq[3]);
    }
}

__global__ void k_finalize(float* stats) {
    int b = threadIdx.x;
    if (b < BB) {
        float s = stats[2*b], sq = stats[2*b+1];
        float mean = s / (float)CHW;
        float var = sq / (float)CHW - mean*mean;
        stats[4 + 2*b] = mean;
        stats[5 + 2*b] = rsqrtf(var + 1e-5f);
    }
}

// ---------------- K3: x -> V_t bf16 [Bf,C,N] and Xnb bf16 [Bf,N,C] ----------------
__global__ __launch_bounds__(256) void k_unshuffle(const float* __restrict__ x, const float* __restrict__ stats,
                                                   ushort* __restrict__ Vt, ushort* __restrict__ Xnb) {
    __shared__ float t[128][65];
    int x0 = blockIdx.x * 64;
    int y  = blockIdx.y;
    int b  = blockIdx.z;
    float mean = stats[4+2*b], istd = stats[5+2*b];
    const float* src = x + (size_t)b*CHW + (size_t)y*WW + x0;
#pragma unroll
    for (int k = 0; k < 32; ++k) {
        int idx = threadIdx.x + 256*k;
        int c = idx >> 6, xl = idx & 63;
        t[c][xl] = src[(size_t)c*HW + xl];
    }
    __syncthreads();
    int i = y >> 3, dy = y & 7;
#pragma unroll
    for (int k = 0; k < 32; ++k) {
        int idx = threadIdx.x + 256*k;
        int xl = idx & 63, c = idx >> 6;
        int xx = x0 + xl;
        int j = xx >> 3, dx = xx & 7;
        int bf = (b << 6) + (dy << 3) + dx;
        int n = i*SH + j;
        Vt[((size_t)bf*CCH + c)*NN + n] = bf16r(t[c][xl]);
    }
#pragma unroll
    for (int k = 0; k < 16; ++k) {
        int idx = threadIdx.x + 256*k;
        int c2 = idx & 63, xl = idx >> 6;
        int c = c2 * 2;
        int xx = x0 + xl;
        int j = xx >> 3, dx = xx & 7;
        int bf = (b << 6) + (dy << 3) + dx;
        int n = i*SH + j;
        float v0 = (t[c][xl]   - mean) * istd;
        float v1 = (t[c+1][xl] - mean) * istd;
        uint32 p = (uint32)bf16r(v0) | ((uint32)bf16r(v1) << 16);
        *(uint32*)&Xnb[((size_t)bf*NN + n)*CCH + c] = p;
    }
}

// ---------------- K4: qkn(bf16) = normalize_rows(Xnb @ wqk) via MFMA ----------------
__global__ __launch_bounds__(256, 4) void k_qk(const ushort* __restrict__ Xnb, const ushort* __restrict__ wqkTb,
                                               ushort* __restrict__ qkn) {
    __shared__ ushort Bs[128*136];
    int bid = blockIdx.x;           // 0..1151
    int bf = bid / 9, tile = bid % 9;
    int n0 = tile * 64;
    int tid = threadIdx.x;
    int wv = tid >> 6, l = tid & 63, quad = l >> 4, l15 = l & 15;
    {
        const uint4* bsrc = (const uint4*)wqkTb;
#pragma unroll
        for (int k = 0; k < 8; ++k) {
            int idx = tid + 256*k;
            int row = idx >> 4, co = idx & 15;
            *(uint4*)&Bs[row*136 + co*8] = bsrc[idx];
        }
    }
    int qb = wv*16;
    const ushort* arow = Xnb + ((size_t)bf*NN + n0 + qb + l15)*CCH + quad*8;
    short8 a[4];
#pragma unroll
    for (int kk = 0; kk < 4; ++kk)
        a[kk] = *(const short8*)(arow + kk*32);
    __syncthreads();
    floatx4 acc[8];
#pragma unroll
    for (int nt = 0; nt < 8; ++nt) acc[nt] = (floatx4){0.f,0.f,0.f,0.f};
#pragma unroll
    for (int kk = 0; kk < 4; ++kk)
#pragma unroll
        for (int nt = 0; nt < 8; ++nt) {
            const short8 bfr = *(const short8*)&Bs[(nt*16 + l15)*136 + kk*32 + quad*8];
            acc[nt] = __builtin_amdgcn_mfma_f32_16x16x32_bf16(a[kk], bfr, acc[nt], 0, 0, 0);
        }
    float ss[4] = {0.f,0.f,0.f,0.f};
#pragma unroll
    for (int nt = 0; nt < 8; ++nt)
#pragma unroll
        for (int r = 0; r < 4; ++r) ss[r] += acc[nt][r]*acc[nt][r];
#pragma unroll
    for (int off = 1; off < 16; off <<= 1)
#pragma unroll
        for (int r = 0; r < 4; ++r) ss[r] += __shfl_xor(ss[r], off);
    float fr[4];
#pragma unroll
    for (int r = 0; r < 4; ++r) fr[r] = 1.f / (sqrtf(ss[r]) + 1e-8f);
    __syncthreads();   // all B-frag reads done before Bs is reused as repack buffer
    ushort* mys = &Bs[qb*128];     // wave-private 16x128 region, stride 128
#pragma unroll
    for (int nt = 0; nt < 8; ++nt)
#pragma unroll
        for (int r = 0; r < 4; ++r)
            mys[(quad*4 + r)*128 + nt*16 + l15] = bf16r(acc[nt][r]*fr[r]);
    uint4* dst = (uint4*)(qkn + ((size_t)bf*NN + n0 + qb)*CCH);
    const uint4* ls = (const uint4*)mys;
#pragma unroll
    for (int k = 0; k < 4; ++k)
        dst[l + 64*k] = ls[l + 64*k];
}

// ---------------- K5: MFMA flash attention  O[bf,n,c] fp32 ----------------
// r7 proved per-wave 3-subtile LDS reuse (+11%); residual was GRID SKEW: 384
// blocks at 2/CU capacity -> 128 CUs held 2 blocks, 128 held 1 (Occupancy 12.8%).
// r8: QBLK=96, 2-wave 128-thread blocks, SAME per-wave structure (3 q-subtiles,
// qb=wv*48). LDS = 17408+18432+13824 = 49,664B -> 3 blocks/CU; grid 768 = 3x256
// EXACTLY uniform, zero skew. 3 independent blocks/CU also fill barrier stalls.
// XCD swizzle kept (same-bf tiles share id%8 residue -> same XCD L2).
__global__ __launch_bounds__(128, 2) void k_attn(const ushort* __restrict__ qkn, const ushort* __restrict__ Vt_g,
                                                 float* __restrict__ O) {
    __shared__ ushort Ks[64*136];
    __shared__ ushort Vs[128*72];
    __shared__ ushort Ps[96*72];
    int id = blockIdx.x;            // 0..767
    int bfl = id & 7, widx = id >> 3;    // widx 0..95
    int tile = widx % 6;
    int bf = ((widx / 6) << 3) | bfl;
    int n0 = tile*96;
    int tid = threadIdx.x;          // 0..127
    int wv = tid >> 6, l = tid & 63, quad = l >> 4, l15 = l & 15;
    int qb = wv*48;

    const uint4* kv_base = (const uint4*)(qkn + (size_t)bf*NN*CCH);   // 16 uint4 per row
    const uint4* vsrc = (const uint4*)(Vt_g + (size_t)bf*CCH*NN);     // [c][n], 72 uint4 per c

    // Q fragments direct from global (prologue only, L2-hot)
    short8 aq[3][4];
#pragma unroll
    for (int qs = 0; qs < 3; ++qs) {
        const ushort* qrow = qkn + ((size_t)bf*NN + n0 + qb + qs*16 + l15)*CCH + quad*8;
#pragma unroll
        for (int kk = 0; kk < 4; ++kk)
            aq[qs][kk] = *(const short8*)(qrow + kk*32);
    }

    floatx4 oacc[3][8];
#pragma unroll
    for (int qs = 0; qs < 3; ++qs)
#pragma unroll
        for (int ct = 0; ct < 8; ++ct) oacc[qs][ct] = (floatx4){0.f,0.f,0.f,0.f};
    float rsum[3][4];
#pragma unroll
    for (int qs = 0; qs < 3; ++qs)
#pragma unroll
        for (int r = 0; r < 4; ++r) rsum[qs][r] = 0.f;
    const float scale = 0.08838834764831845f;   // 1/sqrt(128)

    for (int mt = 0; mt < 9; ++mt) {
        __syncthreads();   // prev compute done reading Ks/Vs
        {
            const uint4* ks = kv_base + (size_t)mt*1024;
            int mo8 = mt*8;
#pragma unroll
            for (int k = 0; k < 8; ++k) {
                int idx = tid + 128*k;
                *(uint4*)&Ks[(idx >> 4)*136 + (idx & 15)*8] = ks[idx];
            }
#pragma unroll
            for (int k = 0; k < 8; ++k) {
                int idx = tid + 128*k;
                *(uint4*)&Vs[(idx >> 3)*72 + (idx & 7)*8] = vsrc[(size_t)(idx >> 3)*72 + mo8 + (idx & 7)];
            }
        }
        __syncthreads();

        floatx4 sc[3][4];
#pragma unroll
        for (int qs = 0; qs < 3; ++qs)
#pragma unroll
            for (int t = 0; t < 4; ++t) sc[qs][t] = (floatx4){0.f,0.f,0.f,0.f};
        __builtin_amdgcn_s_setprio(1);
#pragma unroll
        for (int kk = 0; kk < 4; ++kk)
#pragma unroll
            for (int t = 0; t < 4; ++t) {
                const short8 bk = *(const short8*)&Ks[(t*16 + l15)*136 + kk*32 + quad*8];
#pragma unroll
                for (int qs = 0; qs < 3; ++qs)
                    sc[qs][t] = __builtin_amdgcn_mfma_f32_16x16x32_bf16(aq[qs][kk], bk, sc[qs][t], 0, 0, 0);
            }
        __builtin_amdgcn_s_setprio(0);

#pragma unroll
        for (int qs = 0; qs < 3; ++qs) {
            float pr[4] = {0.f,0.f,0.f,0.f};
#pragma unroll
            for (int t = 0; t < 4; ++t)
#pragma unroll
                for (int r = 0; r < 4; ++r) {
                    float p = __expf((sc[qs][t][r] + 1.f)*scale);
                    Ps[(qb + qs*16 + quad*4 + r)*72 + t*16 + l15] = bf16r(p);   // wave-private rows
                    pr[r] += p;
                }
#pragma unroll
            for (int off = 1; off < 16; off <<= 1)
#pragma unroll
                for (int r = 0; r < 4; ++r) pr[r] += __shfl_xor(pr[r], off);
#pragma unroll
            for (int r = 0; r < 4; ++r) rsum[qs][r] += pr[r];
        }

        short8 ap[3][2];
#pragma unroll
        for (int qs = 0; qs < 3; ++qs) {
            ap[qs][0] = *(const short8*)&Ps[(qb + qs*16 + l15)*72 + quad*8];
            ap[qs][1] = *(const short8*)&Ps[(qb + qs*16 + l15)*72 + 32 + quad*8];
        }
        __builtin_amdgcn_s_setprio(1);
#pragma unroll
        for (int ct = 0; ct < 8; ++ct)
#pragma unroll
            for (int kk2 = 0; kk2 < 2; ++kk2) {
                const short8 bv = *(const short8*)&Vs[(ct*16 + l15)*72 + kk2*32 + quad*8];
#pragma unroll
                for (int qs = 0; qs < 3; ++qs)
                    oacc[qs][ct] = __builtin_amdgcn_mfma_f32_16x16x32_bf16(ap[qs][kk2], bv, oacc[qs][ct], 0, 0, 0);
            }
        __builtin_amdgcn_s_setprio(0);
    }

#pragma unroll
    for (int qs = 0; qs < 3; ++qs) {
        float rinv[4];
#pragma unroll
        for (int r = 0; r < 4; ++r) rinv[r] = 1.f / rsum[qs][r];
#pragma unroll
        for (int ct = 0; ct < 8; ++ct)
#pragma unroll
            for (int r = 0; r < 4; ++r)
                O[((size_t)bf*NN + n0 + qb + qs*16 + quad*4 + r)*CCH + ct*16 + l15] = oacc[qs][ct][r]*rinv[r];
    }
}

// ---------------- K6: yb[b][row][ci_oct16][xp196][8ci] (bf16) = x + shuffle(O) ----------------
__global__ __launch_bounds__(256) void k_shuffle_add(const float* __restrict__ O, const float* __restrict__ x,
                                                     uint4* __restrict__ yb) {
    __shared__ float t[128][65];
    int x0 = blockIdx.x * 64;
    int yy = blockIdx.y;
    int b  = blockIdx.z;
    if (blockIdx.x == 0 && threadIdx.x < 64) {
        int oct = threadIdx.x >> 2, p = threadIdx.x & 3;
        int col = (p < 2) ? p : 192 + p;
        uint4 z; z.x = 0; z.y = 0; z.z = 0; z.w = 0;
        yb[((size_t)(b*192 + yy)*16 + oct)*196 + col] = z;
    }
    int i = yy >> 3, dy = yy & 7;
#pragma unroll
    for (int k = 0; k < 32; ++k) {
        int idx = threadIdx.x + 256*k;
        int c = idx & 127, xl = idx >> 7;
        int xx = x0 + xl;
        int j = xx >> 3, dx = xx & 7;
        int bf = (b << 6) + (dy << 3) + dx;
        int n = i*SH + j;
        t[c][xl] = O[((size_t)bf*NN + n)*CCH + c];
    }
    __syncthreads();
    size_t base = (size_t)b*CHW + (size_t)yy*WW + x0;
#pragma unroll
    for (int k = 0; k < 32; ++k) {
        int idx = threadIdx.x + 256*k;
        int c = idx >> 6, xl = idx & 63;
        t[c][xl] += x[base + (size_t)c*HW + xl];
    }
    __syncthreads();
#pragma unroll
    for (int k = 0; k < 4; ++k) {
        int idx = threadIdx.x + 256*k;
        int xl = idx & 63, oc = idx >> 6;    // oc 0..15 (ci octet)
        uint32 d[4];
#pragma unroll
        for (int j = 0; j < 4; ++j) {
            float f0 = t[oc*8 + 2*j][xl];
            float f1 = t[oc*8 + 2*j + 1][xl];
            d[j] = (uint32)bf16r(f0) | ((uint32)bf16r(f1) << 16);
        }
        uint4 v; v.x = d[0]; v.y = d[1]; v.z = d[2]; v.w = d[3];
        yb[((size_t)(b*192 + yy)*16 + oc)*196 + (x0 + xl + 2)] = v;
    }
}

// ---------------- weight casts ----------------
__global__ __launch_bounds__(256) void k_cast_w(const float* __restrict__ w1, const float* __restrict__ w2,
                                                const float* __restrict__ w3, const float* __restrict__ wqk,
                                                uint4* __restrict__ wb1, uint4* __restrict__ wb2,
                                                uint4* __restrict__ w3b, uint4* __restrict__ wqkTb) {
    int id = blockIdx.x*256 + threadIdx.x;       // 0..18431
    if (blockIdx.y == 2) {
        if (id < 2048) {
            int co = id >> 4, oct = id & 15;
            uint32 r[4];
#pragma unroll
            for (int j = 0; j < 4; ++j) {
                float f0 = w3[(size_t)co*128 + oct*8 + 2*j];
                float f1 = w3[(size_t)co*128 + oct*8 + 2*j + 1];
                r[j] = (uint32)bf16r(f0) | ((uint32)bf16r(f1) << 16);
            }
            uint4 v; v.x = r[0]; v.y = r[1]; v.z = r[2]; v.w = r[3];
            w3b[id] = v;
            int e = co;   // id>>4
            uint32 r2[4];
#pragma unroll
            for (int j = 0; j < 4; ++j) {
                float f0 = wqk[(size_t)(oct*8 + 2*j)*128 + e];
                float f1 = wqk[(size_t)(oct*8 + 2*j + 1)*128 + e];
                r2[j] = (uint32)bf16r(f0) | ((uint32)bf16r(f1) << 16);
            }
            uint4 v2; v2.x = r2[0]; v2.y = r2[1]; v2.z = r2[2]; v2.w = r2[3];
            wqkTb[id] = v2;
        }
        return;
    }
    const float* w = (blockIdx.y == 0) ? w1 : w2;
    uint4* wb = (blockIdx.y == 0) ? wb1 : wb2;
    int co = id & 127;
    int oct = (id >> 7) & 3;
    int chunk = (id >> 9) & 3;
    int tap = id >> 11;                           // 0..8
    int ci0 = chunk*32 + oct*8;
    uint32 r[4];
#pragma unroll
    for (int j = 0; j < 4; ++j) {
        float f0 = w[(size_t)(co*128 + ci0 + 2*j)*9 + tap];
        float f1 = w[(size_t)(co*128 + ci0 + 2*j + 1)*9 + tap];
        r[j] = (uint32)bf16r(f0) | ((uint32)bf16r(f1) << 16);
    }
    uint4 v; v.x = r[0]; v.y = r[1]; v.z = r[2]; v.w = r[3];
    wb[((size_t)(tap*4 + chunk)*4 + oct)*128 + co] = v;
}

// ---------------- K7/K8: 3x3 dilated conv as bf16 MFMA implicit GEMM ----------------
__global__ __launch_bounds__(256, 3) void k_conv3m(const uint4* __restrict__ yb, const uint4* __restrict__ wb,
                                                   const float* __restrict__ bias, void* __restrict__ outp,
                                                   int mode) {
    __shared__ uint4 As[864];          // [r6][oct4][px36] 16B units
    __shared__ uint4 Ws[2][512];       // [oct4][co128]
    int xt = blockIdx.x;               // 0..5
    int rg = blockIdx.y;               // 0..47
    int b  = blockIdx.z;
    int par = rg & 1, g = rg >> 1;
    int y0 = 8*g + par;
    int x0 = xt*32;
    int tid = threadIdx.x;
    int wv = tid >> 6, l = tid & 63, quad = l >> 4, l15 = l & 15;
    int yw = y0 + 2*wv;

    if (mode == 0 && xt == 0) {
        int rowp = y0 + 2*(tid >> 6);
        int oct = (tid >> 2) & 15, p = tid & 3;
        int col = (p < 2) ? p : 192 + p;
        uint4 z; z.x = 0; z.y = 0; z.z = 0; z.w = 0;
        ((uint4*)outp)[((size_t)(b*192 + rowp)*16 + oct)*196 + col] = z;
    }

    floatx4 acc[2][8];
#pragma unroll
    for (int mt = 0; mt < 2; ++mt)
#pragma unroll
        for (int nt = 0; nt < 8; ++nt) acc[mt][nt] = (floatx4){0.f,0.f,0.f,0.f};

    const uint4* ybb = yb + (size_t)b*602112;   // 192*16*196

    for (int chunk = 0; chunk < 4; ++chunk) {
        __syncthreads();
#pragma unroll
        for (int k = 0; k < 4; ++k) {
            int idx = tid + 256*k;
            if (idx < 864) {
                int r = idx / 144;
                int rem = idx - r*144;
                int oct = rem / 36;
                int px = rem - oct*36;
                int grow = y0 - 2 + 2*r;
                uint4 v; v.x = 0; v.y = 0; v.z = 0; v.w = 0;
                if (grow >= 0 && grow < 192)
                    v = ybb[((size_t)grow*16 + chunk*4 + oct)*196 + x0 + px];
                As[idx] = v;
            }
        }
        {
            const uint4* src = wb + (size_t)chunk*512;
            Ws[0][tid]     = src[tid];
            Ws[0][tid+256] = src[tid+256];
        }
        __syncthreads();
#pragma unroll
        for (int tap = 0; tap < 9; ++tap) {
            if (tap < 8) {
                const uint4* src = wb + (size_t)((tap+1)*4 + chunk)*512;
                Ws[(tap+1)&1][tid]     = src[tid];
                Ws[(tap+1)&1][tid+256] = src[tid+256];
            }
            const int ky = tap/3, kx = tap - 3*(tap/3);
            int r = wv + ky;
            const short8 a0 = *(const short8*)&As[(r*4 + quad)*36 + l15 + 2*kx];
            const short8 a1 = *(const short8*)&As[(r*4 + quad)*36 + 16 + l15 + 2*kx];
            const uint4* wbuf = &Ws[tap&1][0];
#pragma unroll
            for (int nt = 0; nt < 8; ++nt) {
                const short8 bf = *(const short8*)&wbuf[quad*128 + nt*16 + l15];
                acc[0][nt] = __builtin_amdgcn_mfma_f32_16x16x32_bf16(a0, bf, acc[0][nt], 0, 0, 0);
                acc[1][nt] = __builtin_amdgcn_mfma_f32_16x16x32_bf16(a1, bf, acc[1][nt], 0, 0, 0);
            }
            __syncthreads();
        }
    }

    if (mode == 0) {
        unsigned short* outb = (unsigned short*)outp;
#pragma unroll
        for (int nt = 0; nt < 8; ++nt) {
            int co = nt*16 + l15;
            float bv = bias[co];
            size_t base = (((size_t)(b*192 + yw)*16 + ((co>>5)*4 + ((co>>3)&3)))*196)*8 + (size_t)(co&7);
#pragma unroll
            for (int mt = 0; mt < 2; ++mt)
#pragma unroll
                for (int rr = 0; rr < 4; ++rr) {
                    int xx = x0 + mt*16 + quad*4 + rr;
                    float v = fmaxf(acc[mt][nt][rr] + bv, 0.f);
                    outb[base + (size_t)(xx+2)*8] = bf16r(v);
                }
        }
    } else {
        unsigned short* outb = (unsigned short*)outp;   // flat NHWC bf16 [b][px][128]
#pragma unroll
        for (int nt = 0; nt < 8; ++nt) {
            int co = nt*16 + l15;
            float bv = bias[co];
#pragma unroll
            for (int mt = 0; mt < 2; ++mt)
#pragma unroll
                for (int rr = 0; rr < 4; ++rr) {
                    int xx = x0 + mt*16 + quad*4 + rr;
                    float v = fmaxf(acc[mt][nt][rr] + bv, 0.f);
                    outb[((size_t)b*36864 + (size_t)yw*192 + xx)*128 + co] = bf16r(v);
                }
        }
    }
}

// ---------------- K9: out = x + (w3 @ h2b) + b3 via MFMA, h2b bf16 NHWC ----------------
__global__ __launch_bounds__(256, 2) void k_conv1x1m(const ushort* __restrict__ h2b, const uint4* __restrict__ w3b,
                                                     const float* __restrict__ b3, const float* __restrict__ x,
                                                     float* __restrict__ out) {
    __shared__ ushort Hs[128*136];
    __shared__ ushort Ws3[128*136];
    int px0 = blockIdx.x * 128;
    int b = blockIdx.y;
    int tid = threadIdx.x;
    int wv = tid >> 6, l = tid & 63, quad = l >> 4, l15 = l & 15;

    {
        const uint4* hsrc = (const uint4*)(h2b + ((size_t)b*36864 + px0)*128);
#pragma unroll
        for (int k = 0; k < 8; ++k) {
            int idx = tid + 256*k;
            int row = idx >> 4, co8 = idx & 15;
            *(uint4*)&Hs[row*136 + co8*8] = hsrc[idx];
            *(uint4*)&Ws3[row*136 + co8*8] = w3b[idx];
        }
    }
    __syncthreads();

    floatx4 oacc[2][8];
#pragma unroll
    for (int mt = 0; mt < 2; ++mt)
#pragma unroll
        for (int nt = 0; nt < 8; ++nt) oacc[mt][nt] = (floatx4){0.f,0.f,0.f,0.f};

#pragma unroll
    for (int kk = 0; kk < 4; ++kk) {
        const short8 aq0 = *(const short8*)&Hs[(wv*32 + l15)*136 + kk*32 + quad*8];
        const short8 aq1 = *(const short8*)&Hs[(wv*32 + 16 + l15)*136 + kk*32 + quad*8];
#pragma unroll
        for (int nt = 0; nt < 8; ++nt) {
            const short8 bw = *(const short8*)&Ws3[(nt*16 + l15)*136 + kk*32 + quad*8];
            oacc[0][nt] = __builtin_amdgcn_mfma_f32_16x16x32_bf16(aq0, bw, oacc[0][nt], 0, 0, 0);
            oacc[1][nt] = __builtin_amdgcn_mfma_f32_16x16x32_bf16(aq1, bw, oacc[1][nt], 0, 0, 0);
        }
    }

#pragma unroll
    for (int nt = 0; nt < 8; ++nt) {
        int co = nt*16 + l15;
        float bv = b3[co];
        size_t pbase = ((size_t)b*128 + co)*HW + px0 + wv*32 + quad*4;
#pragma unroll
        for (int mt = 0; mt < 2; ++mt) {
            const float4 xv = *(const float4*)&x[pbase + mt*16];
            float4 o;
            o.x = oacc[mt][nt][0] + bv + xv.x;
            o.y = oacc[mt][nt][1] + bv + xv.y;
            o.z = oacc[mt][nt][2] + bv + xv.z;
            o.w = oacc[mt][nt][3] + bv + xv.w;
            *(float4*)&out[pbase + mt*16] = o;
        }
    }
}

extern "C" void kernel_launch(void* const* d_in, const int* in_sizes, int n_in,
                              void* d_out, int out_size, void* d_ws, size_t ws_size,
                              hipStream_t stream) {
    (void)in_sizes; (void)n_in; (void)out_size; (void)ws_size;
    const float* x   = (const float*)d_in[0];
    const float* wqk = (const float*)d_in[1];
    const float* w1  = (const float*)d_in[2];
    const float* b1  = (const float*)d_in[3];
    const float* w2  = (const float*)d_in[4];
    const float* b2  = (const float*)d_in[5];
    const float* w3  = (const float*)d_in[6];
    const float* b3  = (const float*)d_in[7];
    float* out = (float*)d_out;
    char* ws = (char*)d_ws;
    float* stats = (float*)ws;
    const size_t SZ = (size_t)BF * NN * CCH * sizeof(float);   // 37,748,736 B
    char* Abase = ws + 256;
    char* Bbase = ws + 256 + SZ;
    char* Cbase = ws + 256 + 2*SZ;
    ushort* Vt  = (ushort*)Abase;
    ushort* Xnb = (ushort*)Bbase;      // bf16
    ushort* qkn = (ushort*)Cbase;
    float*  O   = (float*)Bbase;
    uint4*  yb  = (uint4*)Cbase;
    uint4*  h1b = (uint4*)Abase;
    ushort* h2b = (ushort*)Bbase;      // bf16 NHWC flat, 18.9 MB
    uint4* wb1   = (uint4*)(Abase + 20*1024*1024);
    uint4* wb2   = (uint4*)(Abase + 21*1024*1024);
    uint4* w3b   = (uint4*)(Abase + 22*1024*1024);
    uint4* wqkTb = (uint4*)(Abase + 23*1024*1024);

    hipMemsetAsync(stats, 0, 4*sizeof(float), stream);
    k_reduce     <<<dim3(288, 2),     256, 0, stream>>>(x, stats);
    k_finalize   <<<1, 64,            0, stream>>>(stats);
    k_cast_w     <<<dim3(72, 3),      256, 0, stream>>>(w1, w2, w3, wqk, wb1, wb2, w3b, wqkTb);
    k_unshuffle  <<<dim3(3, 192, 2),  256, 0, stream>>>(x, stats, Vt, Xnb);
    k_qk         <<<1152,             256, 0, stream>>>(Xnb, (const ushort*)wqkTb, qkn);
    k_attn       <<<768,              128, 0, stream>>>(qkn, Vt, O);
    k_shuffle_add<<<dim3(3, 192, 2),  256, 0, stream>>>(O, x, yb);
    k_conv3m     <<<dim3(6, 48, 2),   256, 0, stream>>>(yb,  wb1, b1, (void*)h1b, 0);
    k_conv3m     <<<dim3(6, 48, 2),   256, 0, stream>>>(h1b, wb2, b2, (void*)h2b, 1);
    k_conv1x1m   <<<dim3(288, 2),     256, 0, stream>>>(h2b, w3b, b3, x, out);
}

// Round 13
// 320.611 us; speedup vs baseline: 1.0152x; 1.0152x over previous
//
#include <hip/hip_runtime.h>
#include <math.h>

#define CCH 128
#define HH 192
#define WW 192
#define BB 2
#define HW (HH*WW)        // 36864
#define CHW (CCH*HW)      // 4718592
#define BF 128            // B * f*f = 2*64
#define NN 576            // 24*24
#define SH 24

typedef __attribute__((ext_vector_type(8))) short short8;
typedef __attribute__((ext_vector_type(4))) float floatx4;
typedef unsigned int uint32;
typedef unsigned short ushort;

__device__ __forceinline__ unsigned short bf16r(float f) {
    uint32 u = __float_as_uint(f);
    u += 0x7fffu + ((u >> 16) & 1u);
    return (unsigned short)(u >> 16);
}

// ---------------- K1: per-batch sum / sumsq reduction ----------------
__global__ __launch_bounds__(256) void k_reduce(const float* __restrict__ x, float* __restrict__ stats) {
    int b = blockIdx.y;
    const float4* p = (const float4*)(x + (size_t)b*CHW) + (size_t)blockIdx.x*4096;
    float s = 0.f, sq = 0.f;
#pragma unroll
    for (int k = 0; k < 16; ++k) {
        float4 v = p[threadIdx.x + 256*k];
        s  += v.x + v.y + v.z + v.w;
        sq += v.x*v.x + v.y*v.y + v.z*v.z + v.w*v.w;
    }
    for (int off = 32; off; off >>= 1) { s += __shfl_down(s, off); sq += __shfl_down(sq, off); }
    __shared__ float ls[4], lq[4];
    int wave = threadIdx.x >> 6, lane = threadIdx.x & 63;
    if (lane == 0) { ls[wave] = s; lq[wave] = sq; }
    __syncthreads();
    if (threadIdx.x == 0) {
        atomicAdd(&stats[2*b],   ls[0]+ls[1]+ls[2]+ls[3]);
        atomicAdd(&stats[2*b+1], lq[0]+lq[1]+lq[2]+lq[3]);
    }
}

__global__ void k_finalize(float* stats) {
    int b = threadIdx.x;
    if (b < BB) {
        float s = stats[2*b], sq = stats[2*b+1];
        float mean = s / (float)CHW;
        float var = sq / (float)CHW - mean*mean;
        stats[4 + 2*b] = mean;
        stats[5 + 2*b] = rsqrtf(var + 1e-5f);
    }
}

// ---------------- K3: x -> V_t bf16 [Bf,C,N] and Xnb bf16 [Bf,N,C] ----------------
__global__ __launch_bounds__(256) void k_unshuffle(const float* __restrict__ x, const float* __restrict__ stats,
                                                   ushort* __restrict__ Vt, ushort* __restrict__ Xnb) {
    __shared__ float t[128][65];
    int x0 = blockIdx.x * 64;
    int y  = blockIdx.y;
    int b  = blockIdx.z;
    float mean = stats[4+2*b], istd = stats[5+2*b];
    const float* src = x + (size_t)b*CHW + (size_t)y*WW + x0;
#pragma unroll
    for (int k = 0; k < 32; ++k) {
        int idx = threadIdx.x + 256*k;
        int c = idx >> 6, xl = idx & 63;
        t[c][xl] = src[(size_t)c*HW + xl];
    }
    __syncthreads();
    int i = y >> 3, dy = y & 7;
#pragma unroll
    for (int k = 0; k < 32; ++k) {
        int idx = threadIdx.x + 256*k;
        int xl = idx & 63, c = idx >> 6;
        int xx = x0 + xl;
        int j = xx >> 3, dx = xx & 7;
        int bf = (b << 6) + (dy << 3) + dx;
        int n = i*SH + j;
        Vt[((size_t)bf*CCH + c)*NN + n] = bf16r(t[c][xl]);
    }
#pragma unroll
    for (int k = 0; k < 16; ++k) {
        int idx = threadIdx.x + 256*k;
        int c2 = idx & 63, xl = idx >> 6;
        int c = c2 * 2;
        int xx = x0 + xl;
        int j = xx >> 3, dx = xx & 7;
        int bf = (b << 6) + (dy << 3) + dx;
        int n = i*SH + j;
        float v0 = (t[c][xl]   - mean) * istd;
        float v1 = (t[c+1][xl] - mean) * istd;
        uint32 p = (uint32)bf16r(v0) | ((uint32)bf16r(v1) << 16);
        *(uint32*)&Xnb[((size_t)bf*NN + n)*CCH + c] = p;
    }
}

// ---------------- K4: qkn(bf16) = normalize_rows(Xnb @ wqk) via MFMA ----------------
__global__ __launch_bounds__(256, 4) void k_qk(const ushort* __restrict__ Xnb, const ushort* __restrict__ wqkTb,
                                               ushort* __restrict__ qkn) {
    __shared__ ushort Bs[128*136];
    int bid = blockIdx.x;           // 0..1151
    int bf = bid / 9, tile = bid % 9;
    int n0 = tile * 64;
    int tid = threadIdx.x;
    int wv = tid >> 6, l = tid & 63, quad = l >> 4, l15 = l & 15;
    {
        const uint4* bsrc = (const uint4*)wqkTb;
#pragma unroll
        for (int k = 0; k < 8; ++k) {
            int idx = tid + 256*k;
            int row = idx >> 4, co = idx & 15;
            *(uint4*)&Bs[row*136 + co*8] = bsrc[idx];
        }
    }
    int qb = wv*16;
    const ushort* arow = Xnb + ((size_t)bf*NN + n0 + qb + l15)*CCH + quad*8;
    short8 a[4];
#pragma unroll
    for (int kk = 0; kk < 4; ++kk)
        a[kk] = *(const short8*)(arow + kk*32);
    __syncthreads();
    floatx4 acc[8];
#pragma unroll
    for (int nt = 0; nt < 8; ++nt) acc[nt] = (floatx4){0.f,0.f,0.f,0.f};
#pragma unroll
    for (int kk = 0; kk < 4; ++kk)
#pragma unroll
        for (int nt = 0; nt < 8; ++nt) {
            const short8 bfr = *(const short8*)&Bs[(nt*16 + l15)*136 + kk*32 + quad*8];
            acc[nt] = __builtin_amdgcn_mfma_f32_16x16x32_bf16(a[kk], bfr, acc[nt], 0, 0, 0);
        }
    float ss[4] = {0.f,0.f,0.f,0.f};
#pragma unroll
    for (int nt = 0; nt < 8; ++nt)
#pragma unroll
        for (int r = 0; r < 4; ++r) ss[r] += acc[nt][r]*acc[nt][r];
#pragma unroll
    for (int off = 1; off < 16; off <<= 1)
#pragma unroll
        for (int r = 0; r < 4; ++r) ss[r] += __shfl_xor(ss[r], off);
    float fr[4];
#pragma unroll
    for (int r = 0; r < 4; ++r) fr[r] = 1.f / (sqrtf(ss[r]) + 1e-8f);
    __syncthreads();   // all B-frag reads done before Bs is reused as repack buffer
    ushort* mys = &Bs[qb*128];     // wave-private 16x128 region, stride 128
#pragma unroll
    for (int nt = 0; nt < 8; ++nt)
#pragma unroll
        for (int r = 0; r < 4; ++r)
            mys[(quad*4 + r)*128 + nt*16 + l15] = bf16r(acc[nt][r]*fr[r]);
    uint4* dst = (uint4*)(qkn + ((size_t)bf*NN + n0 + qb)*CCH);
    const uint4* ls = (const uint4*)mys;
#pragma unroll
    for (int k = 0; k < 4; ++k)
        dst[l + 64*k] = ls[l + 64*k];
}

// ---------------- K5: MFMA flash attention  O[bf,n,c] fp32 ----------------
// r7 config verbatim (proven 51.0us): QBLK=192, 4 waves x 3 q-subtiles, grid 384,
// XCD swizzle, 2 blocks/CU, padded LDS, Q direct to reg. r8's 2-wave restructure
// regressed (staging per row doubled, waves/CU 8->6); this family's optimum.
__global__ __launch_bounds__(256, 2) void k_attn(const ushort* __restrict__ qkn, const ushort* __restrict__ Vt_g,
                                                 float* __restrict__ O) {
    __shared__ ushort Ks[64*136];
    __shared__ ushort Vs[128*72];
    __shared__ ushort Ps[192*72];
    int id = blockIdx.x;            // 0..383
    int bfl = id & 7, widx = id >> 3;    // widx 0..47
    int tile = widx % 3;
    int bf = ((widx / 3) << 3) | bfl;
    int n0 = tile*192;
    int tid = threadIdx.x;
    int wv = tid >> 6, l = tid & 63, quad = l >> 4, l15 = l & 15;
    int qb = wv*48;

    const uint4* kv_base = (const uint4*)(qkn + (size_t)bf*NN*CCH);   // 16 uint4 per row
    const uint4* vsrc = (const uint4*)(Vt_g + (size_t)bf*CCH*NN);     // [c][n], 72 uint4 per c

    // Q fragments direct from global (prologue only, L2-hot)
    short8 aq[3][4];
#pragma unroll
    for (int qs = 0; qs < 3; ++qs) {
        const ushort* qrow = qkn + ((size_t)bf*NN + n0 + qb + qs*16 + l15)*CCH + quad*8;
#pragma unroll
        for (int kk = 0; kk < 4; ++kk)
            aq[qs][kk] = *(const short8*)(qrow + kk*32);
    }

    floatx4 oacc[3][8];
#pragma unroll
    for (int qs = 0; qs < 3; ++qs)
#pragma unroll
        for (int ct = 0; ct < 8; ++ct) oacc[qs][ct] = (floatx4){0.f,0.f,0.f,0.f};
    float rsum[3][4];
#pragma unroll
    for (int qs = 0; qs < 3; ++qs)
#pragma unroll
        for (int r = 0; r < 4; ++r) rsum[qs][r] = 0.f;
    const float scale = 0.08838834764831845f;   // 1/sqrt(128)

    for (int mt = 0; mt < 9; ++mt) {
        __syncthreads();   // prev compute done reading Ks/Vs
        {
            const uint4* ks = kv_base + (size_t)mt*1024;
            int mo8 = mt*8;
#pragma unroll
            for (int k = 0; k < 4; ++k) {
                int idx = tid + 256*k;
                *(uint4*)&Ks[(idx >> 4)*136 + (idx & 15)*8] = ks[idx];
            }
#pragma unroll
            for (int k = 0; k < 4; ++k) {
                int idx = tid + 256*k;
                *(uint4*)&Vs[(idx >> 3)*72 + (idx & 7)*8] = vsrc[(size_t)(idx >> 3)*72 + mo8 + (idx & 7)];
            }
        }
        __syncthreads();

        floatx4 sc[3][4];
#pragma unroll
        for (int qs = 0; qs < 3; ++qs)
#pragma unroll
            for (int t = 0; t < 4; ++t) sc[qs][t] = (floatx4){0.f,0.f,0.f,0.f};
        __builtin_amdgcn_s_setprio(1);
#pragma unroll
        for (int kk = 0; kk < 4; ++kk)
#pragma unroll
            for (int t = 0; t < 4; ++t) {
                const short8 bk = *(const short8*)&Ks[(t*16 + l15)*136 + kk*32 + quad*8];
#pragma unroll
                for (int qs = 0; qs < 3; ++qs)
                    sc[qs][t] = __builtin_amdgcn_mfma_f32_16x16x32_bf16(aq[qs][kk], bk, sc[qs][t], 0, 0, 0);
            }
        __builtin_amdgcn_s_setprio(0);

#pragma unroll
        for (int qs = 0; qs < 3; ++qs) {
            float pr[4] = {0.f,0.f,0.f,0.f};
#pragma unroll
            for (int t = 0; t < 4; ++t)
#pragma unroll
                for (int r = 0; r < 4; ++r) {
                    float p = __expf((sc[qs][t][r] + 1.f)*scale);
                    Ps[(qb + qs*16 + quad*4 + r)*72 + t*16 + l15] = bf16r(p);   // wave-private rows
                    pr[r] += p;
                }
#pragma unroll
            for (int off = 1; off < 16; off <<= 1)
#pragma unroll
                for (int r = 0; r < 4; ++r) pr[r] += __shfl_xor(pr[r], off);
#pragma unroll
            for (int r = 0; r < 4; ++r) rsum[qs][r] += pr[r];
        }

        short8 ap[3][2];
#pragma unroll
        for (int qs = 0; qs < 3; ++qs) {
            ap[qs][0] = *(const short8*)&Ps[(qb + qs*16 + l15)*72 + quad*8];
            ap[qs][1] = *(const short8*)&Ps[(qb + qs*16 + l15)*72 + 32 + quad*8];
        }
        __builtin_amdgcn_s_setprio(1);
#pragma unroll
        for (int ct = 0; ct < 8; ++ct)
#pragma unroll
            for (int kk2 = 0; kk2 < 2; ++kk2) {
                const short8 bv = *(const short8*)&Vs[(ct*16 + l15)*72 + kk2*32 + quad*8];
#pragma unroll
                for (int qs = 0; qs < 3; ++qs)
                    oacc[qs][ct] = __builtin_amdgcn_mfma_f32_16x16x32_bf16(ap[qs][kk2], bv, oacc[qs][ct], 0, 0, 0);
            }
        __builtin_amdgcn_s_setprio(0);
    }

#pragma unroll
    for (int qs = 0; qs < 3; ++qs) {
        float rinv[4];
#pragma unroll
        for (int r = 0; r < 4; ++r) rinv[r] = 1.f / rsum[qs][r];
#pragma unroll
        for (int ct = 0; ct < 8; ++ct)
#pragma unroll
            for (int r = 0; r < 4; ++r)
                O[((size_t)bf*NN + n0 + qb + qs*16 + quad*4 + r)*CCH + ct*16 + l15] = oacc[qs][ct][r]*rinv[r];
    }
}

// ---------------- K6: yb[b][row][ci_oct16][xp196][8ci] (bf16) = x + shuffle(O) ----------------
__global__ __launch_bounds__(256) void k_shuffle_add(const float* __restrict__ O, const float* __restrict__ x,
                                                     uint4* __restrict__ yb) {
    __shared__ float t[128][65];
    int x0 = blockIdx.x * 64;
    int yy = blockIdx.y;
    int b  = blockIdx.z;
    if (blockIdx.x == 0 && threadIdx.x < 64) {
        int oct = threadIdx.x >> 2, p = threadIdx.x & 3;
        int col = (p < 2) ? p : 192 + p;
        uint4 z; z.x = 0; z.y = 0; z.z = 0; z.w = 0;
        yb[((size_t)(b*192 + yy)*16 + oct)*196 + col] = z;
    }
    int i = yy >> 3, dy = yy & 7;
#pragma unroll
    for (int k = 0; k < 32; ++k) {
        int idx = threadIdx.x + 256*k;
        int c = idx & 127, xl = idx >> 7;
        int xx = x0 + xl;
        int j = xx >> 3, dx = xx & 7;
        int bf = (b << 6) + (dy << 3) + dx;
        int n = i*SH + j;
        t[c][xl] = O[((size_t)bf*NN + n)*CCH + c];
    }
    __syncthreads();
    size_t base = (size_t)b*CHW + (size_t)yy*WW + x0;
#pragma unroll
    for (int k = 0; k < 32; ++k) {
        int idx = threadIdx.x + 256*k;
        int c = idx >> 6, xl = idx & 63;
        t[c][xl] += x[base + (size_t)c*HW + xl];
    }
    __syncthreads();
#pragma unroll
    for (int k = 0; k < 4; ++k) {
        int idx = threadIdx.x + 256*k;
        int xl = idx & 63, oc = idx >> 6;    // oc 0..15 (ci octet)
        uint32 d[4];
#pragma unroll
        for (int j = 0; j < 4; ++j) {
            float f0 = t[oc*8 + 2*j][xl];
            float f1 = t[oc*8 + 2*j + 1][xl];
            d[j] = (uint32)bf16r(f0) | ((uint32)bf16r(f1) << 16);
        }
        uint4 v; v.x = d[0]; v.y = d[1]; v.z = d[2]; v.w = d[3];
        yb[((size_t)(b*192 + yy)*16 + oc)*196 + (x0 + xl + 2)] = v;
    }
}

// ---------------- weight casts ----------------
__global__ __launch_bounds__(256) void k_cast_w(const float* __restrict__ w1, const float* __restrict__ w2,
                                                const float* __restrict__ w3, const float* __restrict__ wqk,
                                                uint4* __restrict__ wb1, uint4* __restrict__ wb2,
                                                uint4* __restrict__ w3b, uint4* __restrict__ wqkTb) {
    int id = blockIdx.x*256 + threadIdx.x;       // 0..18431
    if (blockIdx.y == 2) {
        if (id < 2048) {
            int co = id >> 4, oct = id & 15;
            uint32 r[4];
#pragma unroll
            for (int j = 0; j < 4; ++j) {
                float f0 = w3[(size_t)co*128 + oct*8 + 2*j];
                float f1 = w3[(size_t)co*128 + oct*8 + 2*j + 1];
                r[j] = (uint32)bf16r(f0) | ((uint32)bf16r(f1) << 16);
            }
            uint4 v; v.x = r[0]; v.y = r[1]; v.z = r[2]; v.w = r[3];
            w3b[id] = v;
            int e = co;   // id>>4
            uint32 r2[4];
#pragma unroll
            for (int j = 0; j < 4; ++j) {
                float f0 = wqk[(size_t)(oct*8 + 2*j)*128 + e];
                float f1 = wqk[(size_t)(oct*8 + 2*j + 1)*128 + e];
                r2[j] = (uint32)bf16r(f0) | ((uint32)bf16r(f1) << 16);
            }
            uint4 v2; v2.x = r2[0]; v2.y = r2[1]; v2.z = r2[2]; v2.w = r2[3];
            wqkTb[id] = v2;
        }
        return;
    }
    const float* w = (blockIdx.y == 0) ? w1 : w2;
    uint4* wb = (blockIdx.y == 0) ? wb1 : wb2;
    int co = id & 127;
    int oct = (id >> 7) & 3;
    int chunk = (id >> 9) & 3;
    int tap = id >> 11;                           // 0..8
    int ci0 = chunk*32 + oct*8;
    uint32 r[4];
#pragma unroll
    for (int j = 0; j < 4; ++j) {
        float f0 = w[(size_t)(co*128 + ci0 + 2*j)*9 + tap];
        float f1 = w[(size_t)(co*128 + ci0 + 2*j + 1)*9 + tap];
        r[j] = (uint32)bf16r(f0) | ((uint32)bf16r(f1) << 16);
    }
    uint4 v; v.x = r[0]; v.y = r[1]; v.z = r[2]; v.w = r[3];
    wb[((size_t)(tap*4 + chunk)*4 + oct)*128 + co] = v;
}

// ---------------- K7/K8: 3x3 dilated conv as bf16 MFMA implicit GEMM ----------------
// r9: weights read DIRECT from global (L1-broadcast: address is wave-invariant,
// 8KB/tap reused by all 576 blocks) instead of Ws LDS double-buffer.
// Removes per-tap barriers (40 -> 8 per block) + Ws staging from the LDS pipe.
__global__ __launch_bounds__(256, 3) void k_conv3m(const uint4* __restrict__ yb, const uint4* __restrict__ wb,
                                                   const float* __restrict__ bias, void* __restrict__ outp,
                                                   int mode) {
    __shared__ uint4 As[864];          // [r6][oct4][px36] 16B units
    int xt = blockIdx.x;               // 0..5
    int rg = blockIdx.y;               // 0..47
    int b  = blockIdx.z;
    int par = rg & 1, g = rg >> 1;
    int y0 = 8*g + par;
    int x0 = xt*32;
    int tid = threadIdx.x;
    int wv = tid >> 6, l = tid & 63, quad = l >> 4, l15 = l & 15;
    int yw = y0 + 2*wv;

    if (mode == 0 && xt == 0) {
        int rowp = y0 + 2*(tid >> 6);
        int oct = (tid >> 2) & 15, p = tid & 3;
        int col = (p < 2) ? p : 192 + p;
        uint4 z; z.x = 0; z.y = 0; z.z = 0; z.w = 0;
        ((uint4*)outp)[((size_t)(b*192 + rowp)*16 + oct)*196 + col] = z;
    }

    floatx4 acc[2][8];
#pragma unroll
    for (int mt = 0; mt < 2; ++mt)
#pragma unroll
        for (int nt = 0; nt < 8; ++nt) acc[mt][nt] = (floatx4){0.f,0.f,0.f,0.f};

    const uint4* ybb = yb + (size_t)b*602112;   // 192*16*196

    for (int chunk = 0; chunk < 4; ++chunk) {
        __syncthreads();   // protect As from previous chunk's readers
#pragma unroll
        for (int k = 0; k < 4; ++k) {
            int idx = tid + 256*k;
            if (idx < 864) {
                int r = idx / 144;
                int rem = idx - r*144;
                int oct = rem / 36;
                int px = rem - oct*36;
                int grow = y0 - 2 + 2*r;
                uint4 v; v.x = 0; v.y = 0; v.z = 0; v.w = 0;
                if (grow >= 0 && grow < 192)
                    v = ybb[((size_t)grow*16 + chunk*4 + oct)*196 + x0 + px];
                As[idx] = v;
            }
        }
        __syncthreads();
#pragma unroll
        for (int tap = 0; tap < 9; ++tap) {
            const int ky = tap/3, kx = tap - 3*(tap/3);
            int r = wv + ky;
            const short8 a0 = *(const short8*)&As[(r*4 + quad)*36 + l15 + 2*kx];
            const short8 a1 = *(const short8*)&As[(r*4 + quad)*36 + 16 + l15 + 2*kx];
            // weight fragments direct from global: wave-invariant address -> L1 broadcast
            const uint4* wsrc = wb + (size_t)((tap*4 + chunk)*4 + quad)*128;
            uint4 wreg[8];
#pragma unroll
            for (int nt = 0; nt < 8; ++nt)
                wreg[nt] = wsrc[nt*16 + l15];
#pragma unroll
            for (int nt = 0; nt < 8; ++nt) {
                const short8 bf = *(const short8*)&wreg[nt];
                acc[0][nt] = __builtin_amdgcn_mfma_f32_16x16x32_bf16(a0, bf, acc[0][nt], 0, 0, 0);
                acc[1][nt] = __builtin_amdgcn_mfma_f32_16x16x32_bf16(a1, bf, acc[1][nt], 0, 0, 0);
            }
        }
    }

    if (mode == 0) {
        unsigned short* outb = (unsigned short*)outp;
#pragma unroll
        for (int nt = 0; nt < 8; ++nt) {
            int co = nt*16 + l15;
            float bv = bias[co];
            size_t base = (((size_t)(b*192 + yw)*16 + ((co>>5)*4 + ((co>>3)&3)))*196)*8 + (size_t)(co&7);
#pragma unroll
            for (int mt = 0; mt < 2; ++mt)
#pragma unroll
                for (int rr = 0; rr < 4; ++rr) {
                    int xx = x0 + mt*16 + quad*4 + rr;
                    float v = fmaxf(acc[mt][nt][rr] + bv, 0.f);
                    outb[base + (size_t)(xx+2)*8] = bf16r(v);
                }
        }
    } else {
        unsigned short* outb = (unsigned short*)outp;   // flat NHWC bf16 [b][px][128]
#pragma unroll
        for (int nt = 0; nt < 8; ++nt) {
            int co = nt*16 + l15;
            float bv = bias[co];
#pragma unroll
            for (int mt = 0; mt < 2; ++mt)
#pragma unroll
                for (int rr = 0; rr < 4; ++rr) {
                    int xx = x0 + mt*16 + quad*4 + rr;
                    float v = fmaxf(acc[mt][nt][rr] + bv, 0.f);
                    outb[((size_t)b*36864 + (size_t)yw*192 + xx)*128 + co] = bf16r(v);
                }
        }
    }
}

// ---------------- K9: out = x + (w3 @ h2b) + b3 via MFMA, h2b bf16 NHWC ----------------
__global__ __launch_bounds__(256, 2) void k_conv1x1m(const ushort* __restrict__ h2b, const uint4* __restrict__ w3b,
                                                     const float* __restrict__ b3, const float* __restrict__ x,
                                                     float* __restrict__ out) {
    __shared__ ushort Hs[128*136];
    __shared__ ushort Ws3[128*136];
    int px0 = blockIdx.x * 128;
    int b = blockIdx.y;
    int tid = threadIdx.x;
    int wv = tid >> 6, l = tid & 63, quad = l >> 4, l15 = l & 15;

    {
        const uint4* hsrc = (const uint4*)(h2b + ((size_t)b*36864 + px0)*128);
#pragma unroll
        for (int k = 0; k < 8; ++k) {
            int idx = tid + 256*k;
            int row = idx >> 4, co8 = idx & 15;
            *(uint4*)&Hs[row*136 + co8*8] = hsrc[idx];
            *(uint4*)&Ws3[row*136 + co8*8] = w3b[idx];
        }
    }
    __syncthreads();

    floatx4 oacc[2][8];
#pragma unroll
    for (int mt = 0; mt < 2; ++mt)
#pragma unroll
        for (int nt = 0; nt < 8; ++nt) oacc[mt][nt] = (floatx4){0.f,0.f,0.f,0.f};

#pragma unroll
    for (int kk = 0; kk < 4; ++kk) {
        const short8 aq0 = *(const short8*)&Hs[(wv*32 + l15)*136 + kk*32 + quad*8];
        const short8 aq1 = *(const short8*)&Hs[(wv*32 + 16 + l15)*136 + kk*32 + quad*8];
#pragma unroll
        for (int nt = 0; nt < 8; ++nt) {
            const short8 bw = *(const short8*)&Ws3[(nt*16 + l15)*136 + kk*32 + quad*8];
            oacc[0][nt] = __builtin_amdgcn_mfma_f32_16x16x32_bf16(aq0, bw, oacc[0][nt], 0, 0, 0);
            oacc[1][nt] = __builtin_amdgcn_mfma_f32_16x16x32_bf16(aq1, bw, oacc[1][nt], 0, 0, 0);
        }
    }

#pragma unroll
    for (int nt = 0; nt < 8; ++nt) {
        int co = nt*16 + l15;
        float bv = b3[co];
        size_t pbase = ((size_t)b*128 + co)*HW + px0 + wv*32 + quad*4;
#pragma unroll
        for (int mt = 0; mt < 2; ++mt) {
            const float4 xv = *(const float4*)&x[pbase + mt*16];
            float4 o;
            o.x = oacc[mt][nt][0] + bv + xv.x;
            o.y = oacc[mt][nt][1] + bv + xv.y;
            o.z = oacc[mt][nt][2] + bv + xv.z;
            o.w = oacc[mt][nt][3] + bv + xv.w;
            *(float4*)&out[pbase + mt*16] = o;
        }
    }
}

extern "C" void kernel_launch(void* const* d_in, const int* in_sizes, int n_in,
                              void* d_out, int out_size, void* d_ws, size_t ws_size,
                              hipStream_t stream) {
    (void)in_sizes; (void)n_in; (void)out_size; (void)ws_size;
    const float* x   = (const float*)d_in[0];
    const float* wqk = (const float*)d_in[1];
    const float* w1  = (const float*)d_in[2];
    const float* b1  = (const float*)d_in[3];
    const float* w2  = (const float*)d_in[4];
    const float* b2  = (const float*)d_in[5];
    const float* w3  = (const float*)d_in[6];
    const float* b3  = (const float*)d_in[7];
    float* out = (float*)d_out;
    char* ws = (char*)d_ws;
    float* stats = (float*)ws;
    const size_t SZ = (size_t)BF * NN * CCH * sizeof(float);   // 37,748,736 B
    char* Abase = ws + 256;
    char* Bbase = ws + 256 + SZ;
    char* Cbase = ws + 256 + 2*SZ;
    ushort* Vt  = (ushort*)Abase;
    ushort* Xnb = (ushort*)Bbase;      // bf16
    ushort* qkn = (ushort*)Cbase;
    float*  O   = (float*)Bbase;
    uint4*  yb  = (uint4*)Cbase;
    uint4*  h1b = (uint4*)Abase;
    ushort* h2b = (ushort*)Bbase;      // bf16 NHWC flat, 18.9 MB
    uint4* wb1   = (uint4*)(Abase + 20*1024*1024);
    uint4* wb2   = (uint4*)(Abase + 21*1024*1024);
    uint4* w3b   = (uint4*)(Abase + 22*1024*1024);
    uint4* wqkTb = (uint4*)(Abase + 23*1024*1024);

    hipMemsetAsync(stats, 0, 4*sizeof(float), stream);
    k_reduce     <<<dim3(288, 2),     256, 0, stream>>>(x, stats);
    k_finalize   <<<1, 64,            0, stream>>>(stats);
    k_cast_w     <<<dim3(72, 3),      256, 0, stream>>>(w1, w2, w3, wqk, wb1, wb2, w3b, wqkTb);
    k_unshuffle  <<<dim3(3, 192, 2),  256, 0, stream>>>(x, stats, Vt, Xnb);
    k_qk         <<<1152,             256, 0, stream>>>(Xnb, (const ushort*)wqkTb, qkn);
    k_attn       <<<384,              256, 0, stream>>>(qkn, Vt, O);
    k_shuffle_add<<<dim3(3, 192, 2),  256, 0, stream>>>(O, x, yb);
    k_conv3m     <<<dim3(6, 48, 2),   256, 0, stream>>>(yb,  wb1, b1, (void*)h1b, 0);
    k_conv3m     <<<dim3(6, 48, 2),   256, 0, stream>>>(h1b, wb2, b2, (void*)h2b, 1);
    k_conv1x1m   <<<dim3(288, 2),     256, 0, stream>>>(h2b, w3b, b3, x, out);
}

// Round 16
// 293.998 us; speedup vs baseline: 1.1071x; 1.0905x over previous
//
#include <hip/hip_runtime.h>
#include <math.h>

#define CCH 128
#define HH 192
#define WW 192
#define BB 2
#define HW (HH*WW)        // 36864
#define CHW (CCH*HW)      // 4718592
#define BF 128            // B * f*f = 2*64
#define NN 576            // 24*24
#define SH 24

typedef __attribute__((ext_vector_type(8))) short short8;
typedef __attribute__((ext_vector_type(4))) float floatx4;
typedef unsigned int uint32;
typedef unsigned short ushort;

__device__ __forceinline__ unsigned short bf16r(float f) {
    uint32 u = __float_as_uint(f);
    u += 0x7fffu + ((u >> 16) & 1u);
    return (unsigned short)(u >> 16);
}

// ---------------- K1: per-batch sum / sumsq reduction ----------------
__global__ __launch_bounds__(256) void k_reduce(const float* __restrict__ x, float* __restrict__ stats) {
    int b = blockIdx.y;
    const float4* p = (const float4*)(x + (size_t)b*CHW) + (size_t)blockIdx.x*4096;
    float s = 0.f, sq = 0.f;
#pragma unroll
    for (int k = 0; k < 16; ++k) {
        float4 v = p[threadIdx.x + 256*k];
        s  += v.x + v.y + v.z + v.w;
        sq += v.x*v.x + v.y*v.y + v.z*v.z + v.w*v.w;
    }
    for (int off = 32; off; off >>= 1) { s += __shfl_down(s, off); sq += __shfl_down(sq, off); }
    __shared__ float ls[4], lq[4];
    int wave = threadIdx.x >> 6, lane = threadIdx.x & 63;
    if (lane == 0) { ls[wave] = s; lq[wave] = sq; }
    __syncthreads();
    if (threadIdx.x == 0) {
        atomicAdd(&stats[2*b],   ls[0]+ls[1]+ls[2]+ls[3]);
        atomicAdd(&stats[2*b+1], lq[0]+lq[1]+lq[2]+lq[3]);
    }
}

__global__ void k_finalize(float* stats) {
    int b = threadIdx.x;
    if (b < BB) {
        float s = stats[2*b], sq = stats[2*b+1];
        float mean = s / (float)CHW;
        float var = sq / (float)CHW - mean*mean;
        stats[4 + 2*b] = mean;
        stats[5 + 2*b] = rsqrtf(var + 1e-5f);
    }
}

// ---------------- K3: x -> V_t bf16 [Bf,C,N] and Xnb bf16 [Bf,N,C] ----------------
__global__ __launch_bounds__(256) void k_unshuffle(const float* __restrict__ x, const float* __restrict__ stats,
                                                   ushort* __restrict__ Vt, ushort* __restrict__ Xnb) {
    __shared__ float t[128][65];
    int x0 = blockIdx.x * 64;
    int y  = blockIdx.y;
    int b  = blockIdx.z;
    float mean = stats[4+2*b], istd = stats[5+2*b];
    const float* src = x + (size_t)b*CHW + (size_t)y*WW + x0;
#pragma unroll
    for (int k = 0; k < 32; ++k) {
        int idx = threadIdx.x + 256*k;
        int c = idx >> 6, xl = idx & 63;
        t[c][xl] = src[(size_t)c*HW + xl];
    }
    __syncthreads();
    int i = y >> 3, dy = y & 7;
#pragma unroll
    for (int k = 0; k < 32; ++k) {
        int idx = threadIdx.x + 256*k;
        int xl = idx & 63, c = idx >> 6;
        int xx = x0 + xl;
        int j = xx >> 3, dx = xx & 7;
        int bf = (b << 6) + (dy << 3) + dx;
        int n = i*SH + j;
        Vt[((size_t)bf*CCH + c)*NN + n] = bf16r(t[c][xl]);
    }
#pragma unroll
    for (int k = 0; k < 16; ++k) {
        int idx = threadIdx.x + 256*k;
        int c2 = idx & 63, xl = idx >> 6;
        int c = c2 * 2;
        int xx = x0 + xl;
        int j = xx >> 3, dx = xx & 7;
        int bf = (b << 6) + (dy << 3) + dx;
        int n = i*SH + j;
        float v0 = (t[c][xl]   - mean) * istd;
        float v1 = (t[c+1][xl] - mean) * istd;
        uint32 p = (uint32)bf16r(v0) | ((uint32)bf16r(v1) << 16);
        *(uint32*)&Xnb[((size_t)bf*NN + n)*CCH + c] = p;
    }
}

// ---------------- K4: qkn(bf16) = normalize_rows(Xnb @ wqk) via MFMA ----------------
__global__ __launch_bounds__(256, 4) void k_qk(const ushort* __restrict__ Xnb, const ushort* __restrict__ wqkTb,
                                               ushort* __restrict__ qkn) {
    __shared__ ushort Bs[128*136];
    int bid = blockIdx.x;           // 0..1151
    int bf = bid / 9, tile = bid % 9;
    int n0 = tile * 64;
    int tid = threadIdx.x;
    int wv = tid >> 6, l = tid & 63, quad = l >> 4, l15 = l & 15;
    {
        const uint4* bsrc = (const uint4*)wqkTb;
#pragma unroll
        for (int k = 0; k < 8; ++k) {
            int idx = tid + 256*k;
            int row = idx >> 4, co = idx & 15;
            *(uint4*)&Bs[row*136 + co*8] = bsrc[idx];
        }
    }
    int qb = wv*16;
    const ushort* arow = Xnb + ((size_t)bf*NN + n0 + qb + l15)*CCH + quad*8;
    short8 a[4];
#pragma unroll
    for (int kk = 0; kk < 4; ++kk)
        a[kk] = *(const short8*)(arow + kk*32);
    __syncthreads();
    floatx4 acc[8];
#pragma unroll
    for (int nt = 0; nt < 8; ++nt) acc[nt] = (floatx4){0.f,0.f,0.f,0.f};
#pragma unroll
    for (int kk = 0; kk < 4; ++kk)
#pragma unroll
        for (int nt = 0; nt < 8; ++nt) {
            const short8 bfr = *(const short8*)&Bs[(nt*16 + l15)*136 + kk*32 + quad*8];
            acc[nt] = __builtin_amdgcn_mfma_f32_16x16x32_bf16(a[kk], bfr, acc[nt], 0, 0, 0);
        }
    float ss[4] = {0.f,0.f,0.f,0.f};
#pragma unroll
    for (int nt = 0; nt < 8; ++nt)
#pragma unroll
        for (int r = 0; r < 4; ++r) ss[r] += acc[nt][r]*acc[nt][r];
#pragma unroll
    for (int off = 1; off < 16; off <<= 1)
#pragma unroll
        for (int r = 0; r < 4; ++r) ss[r] += __shfl_xor(ss[r], off);
    float fr[4];
#pragma unroll
    for (int r = 0; r < 4; ++r) fr[r] = 1.f / (sqrtf(ss[r]) + 1e-8f);
    __syncthreads();   // all B-frag reads done before Bs is reused as repack buffer
    ushort* mys = &Bs[qb*128];     // wave-private 16x128 region, stride 128
#pragma unroll
    for (int nt = 0; nt < 8; ++nt)
#pragma unroll
        for (int r = 0; r < 4; ++r)
            mys[(quad*4 + r)*128 + nt*16 + l15] = bf16r(acc[nt][r]*fr[r]);
    uint4* dst = (uint4*)(qkn + ((size_t)bf*NN + n0 + qb)*CCH);
    const uint4* ls = (const uint4*)mys;
#pragma unroll
    for (int k = 0; k < 4; ++k)
        dst[l + 64*k] = ls[l + 64*k];
}

// ---------------- K5: MFMA flash attention  O[bf,n,c] fp32 ----------------
// r7 config verbatim (proven 51.0us): QBLK=192, 4 waves x 3 q-subtiles, grid 384,
// XCD swizzle, 2 blocks/CU, padded LDS, Q direct to reg.
__global__ __launch_bounds__(256, 2) void k_attn(const ushort* __restrict__ qkn, const ushort* __restrict__ Vt_g,
                                                 float* __restrict__ O) {
    __shared__ ushort Ks[64*136];
    __shared__ ushort Vs[128*72];
    __shared__ ushort Ps[192*72];
    int id = blockIdx.x;            // 0..383
    int bfl = id & 7, widx = id >> 3;    // widx 0..47
    int tile = widx % 3;
    int bf = ((widx / 3) << 3) | bfl;
    int n0 = tile*192;
    int tid = threadIdx.x;
    int wv = tid >> 6, l = tid & 63, quad = l >> 4, l15 = l & 15;
    int qb = wv*48;

    const uint4* kv_base = (const uint4*)(qkn + (size_t)bf*NN*CCH);   // 16 uint4 per row
    const uint4* vsrc = (const uint4*)(Vt_g + (size_t)bf*CCH*NN);     // [c][n], 72 uint4 per c

    // Q fragments direct from global (prologue only, L2-hot)
    short8 aq[3][4];
#pragma unroll
    for (int qs = 0; qs < 3; ++qs) {
        const ushort* qrow = qkn + ((size_t)bf*NN + n0 + qb + qs*16 + l15)*CCH + quad*8;
#pragma unroll
        for (int kk = 0; kk < 4; ++kk)
            aq[qs][kk] = *(const short8*)(qrow + kk*32);
    }

    floatx4 oacc[3][8];
#pragma unroll
    for (int qs = 0; qs < 3; ++qs)
#pragma unroll
        for (int ct = 0; ct < 8; ++ct) oacc[qs][ct] = (floatx4){0.f,0.f,0.f,0.f};
    float rsum[3][4];
#pragma unroll
    for (int qs = 0; qs < 3; ++qs)
#pragma unroll
        for (int r = 0; r < 4; ++r) rsum[qs][r] = 0.f;
    const float scale = 0.08838834764831845f;   // 1/sqrt(128)

    for (int mt = 0; mt < 9; ++mt) {
        __syncthreads();   // prev compute done reading Ks/Vs
        {
            const uint4* ks = kv_base + (size_t)mt*1024;
            int mo8 = mt*8;
#pragma unroll
            for (int k = 0; k < 4; ++k) {
                int idx = tid + 256*k;
                *(uint4*)&Ks[(idx >> 4)*136 + (idx & 15)*8] = ks[idx];
            }
#pragma unroll
            for (int k = 0; k < 4; ++k) {
                int idx = tid + 256*k;
                *(uint4*)&Vs[(idx >> 3)*72 + (idx & 7)*8] = vsrc[(size_t)(idx >> 3)*72 + mo8 + (idx & 7)];
            }
        }
        __syncthreads();

        floatx4 sc[3][4];
#pragma unroll
        for (int qs = 0; qs < 3; ++qs)
#pragma unroll
            for (int t = 0; t < 4; ++t) sc[qs][t] = (floatx4){0.f,0.f,0.f,0.f};
        __builtin_amdgcn_s_setprio(1);
#pragma unroll
        for (int kk = 0; kk < 4; ++kk)
#pragma unroll
            for (int t = 0; t < 4; ++t) {
                const short8 bk = *(const short8*)&Ks[(t*16 + l15)*136 + kk*32 + quad*8];
#pragma unroll
                for (int qs = 0; qs < 3; ++qs)
                    sc[qs][t] = __builtin_amdgcn_mfma_f32_16x16x32_bf16(aq[qs][kk], bk, sc[qs][t], 0, 0, 0);
            }
        __builtin_amdgcn_s_setprio(0);

#pragma unroll
        for (int qs = 0; qs < 3; ++qs) {
            float pr[4] = {0.f,0.f,0.f,0.f};
#pragma unroll
            for (int t = 0; t < 4; ++t)
#pragma unroll
                for (int r = 0; r < 4; ++r) {
                    float p = __expf((sc[qs][t][r] + 1.f)*scale);
                    Ps[(qb + qs*16 + quad*4 + r)*72 + t*16 + l15] = bf16r(p);   // wave-private rows
                    pr[r] += p;
                }
#pragma unroll
            for (int off = 1; off < 16; off <<= 1)
#pragma unroll
                for (int r = 0; r < 4; ++r) pr[r] += __shfl_xor(pr[r], off);
#pragma unroll
            for (int r = 0; r < 4; ++r) rsum[qs][r] += pr[r];
        }

        short8 ap[3][2];
#pragma unroll
        for (int qs = 0; qs < 3; ++qs) {
            ap[qs][0] = *(const short8*)&Ps[(qb + qs*16 + l15)*72 + quad*8];
            ap[qs][1] = *(const short8*)&Ps[(qb + qs*16 + l15)*72 + 32 + quad*8];
        }
        __builtin_amdgcn_s_setprio(1);
#pragma unroll
        for (int ct = 0; ct < 8; ++ct)
#pragma unroll
            for (int kk2 = 0; kk2 < 2; ++kk2) {
                const short8 bv = *(const short8*)&Vs[(ct*16 + l15)*72 + kk2*32 + quad*8];
#pragma unroll
                for (int qs = 0; qs < 3; ++qs)
                    oacc[qs][ct] = __builtin_amdgcn_mfma_f32_16x16x32_bf16(ap[qs][kk2], bv, oacc[qs][ct], 0, 0, 0);
            }
        __builtin_amdgcn_s_setprio(0);
    }

#pragma unroll
    for (int qs = 0; qs < 3; ++qs) {
        float rinv[4];
#pragma unroll
        for (int r = 0; r < 4; ++r) rinv[r] = 1.f / rsum[qs][r];
#pragma unroll
        for (int ct = 0; ct < 8; ++ct)
#pragma unroll
            for (int r = 0; r < 4; ++r)
                O[((size_t)bf*NN + n0 + qb + qs*16 + quad*4 + r)*CCH + ct*16 + l15] = oacc[qs][ct][r]*rinv[r];
    }
}

// ---------------- K6: yb[b][row][ci_oct16][xp196][8ci] (bf16) = x + shuffle(O) ----------------
__global__ __launch_bounds__(256) void k_shuffle_add(const float* __restrict__ O, const float* __restrict__ x,
                                                     uint4* __restrict__ yb) {
    __shared__ float t[128][65];
    int x0 = blockIdx.x * 64;
    int yy = blockIdx.y;
    int b  = blockIdx.z;
    if (blockIdx.x == 0 && threadIdx.x < 64) {
        int oct = threadIdx.x >> 2, p = threadIdx.x & 3;
        int col = (p < 2) ? p : 192 + p;
        uint4 z; z.x = 0; z.y = 0; z.z = 0; z.w = 0;
        yb[((size_t)(b*192 + yy)*16 + oct)*196 + col] = z;
    }
    int i = yy >> 3, dy = yy & 7;
#pragma unroll
    for (int k = 0; k < 32; ++k) {
        int idx = threadIdx.x + 256*k;
        int c = idx & 127, xl = idx >> 7;
        int xx = x0 + xl;
        int j = xx >> 3, dx = xx & 7;
        int bf = (b << 6) + (dy << 3) + dx;
        int n = i*SH + j;
        t[c][xl] = O[((size_t)bf*NN + n)*CCH + c];
    }
    __syncthreads();
    size_t base = (size_t)b*CHW + (size_t)yy*WW + x0;
#pragma unroll
    for (int k = 0; k < 32; ++k) {
        int idx = threadIdx.x + 256*k;
        int c = idx >> 6, xl = idx & 63;
        t[c][xl] += x[base + (size_t)c*HW + xl];
    }
    __syncthreads();
#pragma unroll
    for (int k = 0; k < 4; ++k) {
        int idx = threadIdx.x + 256*k;
        int xl = idx & 63, oc = idx >> 6;    // oc 0..15 (ci octet)
        uint32 d[4];
#pragma unroll
        for (int j = 0; j < 4; ++j) {
            float f0 = t[oc*8 + 2*j][xl];
            float f1 = t[oc*8 + 2*j + 1][xl];
            d[j] = (uint32)bf16r(f0) | ((uint32)bf16r(f1) << 16);
        }
        uint4 v; v.x = d[0]; v.y = d[1]; v.z = d[2]; v.w = d[3];
        yb[((size_t)(b*192 + yy)*16 + oc)*196 + (x0 + xl + 2)] = v;
    }
}

// ---------------- weight casts ----------------
__global__ __launch_bounds__(256) void k_cast_w(const float* __restrict__ w1, const float* __restrict__ w2,
                                                const float* __restrict__ w3, const float* __restrict__ wqk,
                                                uint4* __restrict__ wb1, uint4* __restrict__ wb2,
                                                uint4* __restrict__ w3b, uint4* __restrict__ wqkTb) {
    int id = blockIdx.x*256 + threadIdx.x;       // 0..18431
    if (blockIdx.y == 2) {
        if (id < 2048) {
            int co = id >> 4, oct = id & 15;
            uint32 r[4];
#pragma unroll
            for (int j = 0; j < 4; ++j) {
                float f0 = w3[(size_t)co*128 + oct*8 + 2*j];
                float f1 = w3[(size_t)co*128 + oct*8 + 2*j + 1];
                r[j] = (uint32)bf16r(f0) | ((uint32)bf16r(f1) << 16);
            }
            uint4 v; v.x = r[0]; v.y = r[1]; v.z = r[2]; v.w = r[3];
            w3b[id] = v;
            int e = co;   // id>>4
            uint32 r2[4];
#pragma unroll
            for (int j = 0; j < 4; ++j) {
                float f0 = wqk[(size_t)(oct*8 + 2*j)*128 + e];
                float f1 = wqk[(size_t)(oct*8 + 2*j + 1)*128 + e];
                r2[j] = (uint32)bf16r(f0) | ((uint32)bf16r(f1) << 16);
            }
            uint4 v2; v2.x = r2[0]; v2.y = r2[1]; v2.z = r2[2]; v2.w = r2[3];
            wqkTb[id] = v2;
        }
        return;
    }
    const float* w = (blockIdx.y == 0) ? w1 : w2;
    uint4* wb = (blockIdx.y == 0) ? wb1 : wb2;
    int co = id & 127;
    int oct = (id >> 7) & 3;
    int chunk = (id >> 9) & 3;
    int tap = id >> 11;                           // 0..8
    int ci0 = chunk*32 + oct*8;
    uint32 r[4];
#pragma unroll
    for (int j = 0; j < 4; ++j) {
        float f0 = w[(size_t)(co*128 + ci0 + 2*j)*9 + tap];
        float f1 = w[(size_t)(co*128 + ci0 + 2*j + 1)*9 + tap];
        r[j] = (uint32)bf16r(f0) | ((uint32)bf16r(f1) << 16);
    }
    uint4 v; v.x = r[0]; v.y = r[1]; v.z = r[2]; v.w = r[3];
    wb[((size_t)(tap*4 + chunk)*4 + oct)*128 + co] = v;
}

// ---------------- K7/K8: 3x3 dilated conv as bf16 MFMA implicit GEMM ----------------
// r7 Ws[2] LDS double-buffer (r13 measured direct-global at 55us: serial
// load->wait->MFMA latency chain; the double-buffer IS the software pipeline).
__global__ __launch_bounds__(256, 3) void k_conv3m(const uint4* __restrict__ yb, const uint4* __restrict__ wb,
                                                   const float* __restrict__ bias, void* __restrict__ outp,
                                                   int mode) {
    __shared__ uint4 As[864];          // [r6][oct4][px36] 16B units
    __shared__ uint4 Ws[2][512];       // [oct4][co128]
    int xt = blockIdx.x;               // 0..5
    int rg = blockIdx.y;               // 0..47
    int b  = blockIdx.z;
    int par = rg & 1, g = rg >> 1;
    int y0 = 8*g + par;
    int x0 = xt*32;
    int tid = threadIdx.x;
    int wv = tid >> 6, l = tid & 63, quad = l >> 4, l15 = l & 15;
    int yw = y0 + 2*wv;

    if (mode == 0 && xt == 0) {
        int rowp = y0 + 2*(tid >> 6);
        int oct = (tid >> 2) & 15, p = tid & 3;
        int col = (p < 2) ? p : 192 + p;
        uint4 z; z.x = 0; z.y = 0; z.z = 0; z.w = 0;
        ((uint4*)outp)[((size_t)(b*192 + rowp)*16 + oct)*196 + col] = z;
    }

    floatx4 acc[2][8];
#pragma unroll
    for (int mt = 0; mt < 2; ++mt)
#pragma unroll
        for (int nt = 0; nt < 8; ++nt) acc[mt][nt] = (floatx4){0.f,0.f,0.f,0.f};

    const uint4* ybb = yb + (size_t)b*602112;   // 192*16*196

    for (int chunk = 0; chunk < 4; ++chunk) {
        __syncthreads();
#pragma unroll
        for (int k = 0; k < 4; ++k) {
            int idx = tid + 256*k;
            if (idx < 864) {
                int r = idx / 144;
                int rem = idx - r*144;
                int oct = rem / 36;
                int px = rem - oct*36;
                int grow = y0 - 2 + 2*r;
                uint4 v; v.x = 0; v.y = 0; v.z = 0; v.w = 0;
                if (grow >= 0 && grow < 192)
                    v = ybb[((size_t)grow*16 + chunk*4 + oct)*196 + x0 + px];
                As[idx] = v;
            }
        }
        {
            const uint4* src = wb + (size_t)chunk*512;
            Ws[0][tid]     = src[tid];
            Ws[0][tid+256] = src[tid+256];
        }
        __syncthreads();
#pragma unroll
        for (int tap = 0; tap < 9; ++tap) {
            if (tap < 8) {
                const uint4* src = wb + (size_t)((tap+1)*4 + chunk)*512;
                Ws[(tap+1)&1][tid]     = src[tid];
                Ws[(tap+1)&1][tid+256] = src[tid+256];
            }
            const int ky = tap/3, kx = tap - 3*(tap/3);
            int r = wv + ky;
            const short8 a0 = *(const short8*)&As[(r*4 + quad)*36 + l15 + 2*kx];
            const short8 a1 = *(const short8*)&As[(r*4 + quad)*36 + 16 + l15 + 2*kx];
            const uint4* wbuf = &Ws[tap&1][0];
#pragma unroll
            for (int nt = 0; nt < 8; ++nt) {
                const short8 bf = *(const short8*)&wbuf[quad*128 + nt*16 + l15];
                acc[0][nt] = __builtin_amdgcn_mfma_f32_16x16x32_bf16(a0, bf, acc[0][nt], 0, 0, 0);
                acc[1][nt] = __builtin_amdgcn_mfma_f32_16x16x32_bf16(a1, bf, acc[1][nt], 0, 0, 0);
            }
            __syncthreads();
        }
    }

    if (mode == 0) {
        unsigned short* outb = (unsigned short*)outp;
#pragma unroll
        for (int nt = 0; nt < 8; ++nt) {
            int co = nt*16 + l15;
            float bv = bias[co];
            size_t base = (((size_t)(b*192 + yw)*16 + ((co>>5)*4 + ((co>>3)&3)))*196)*8 + (size_t)(co&7);
#pragma unroll
            for (int mt = 0; mt < 2; ++mt)
#pragma unroll
                for (int rr = 0; rr < 4; ++rr) {
                    int xx = x0 + mt*16 + quad*4 + rr;
                    float v = fmaxf(acc[mt][nt][rr] + bv, 0.f);
                    outb[base + (size_t)(xx+2)*8] = bf16r(v);
                }
        }
    } else {
        unsigned short* outb = (unsigned short*)outp;   // flat NHWC bf16 [b][px][128]
#pragma unroll
        for (int nt = 0; nt < 8; ++nt) {
            int co = nt*16 + l15;
            float bv = bias[co];
#pragma unroll
            for (int mt = 0; mt < 2; ++mt)
#pragma unroll
                for (int rr = 0; rr < 4; ++rr) {
                    int xx = x0 + mt*16 + quad*4 + rr;
                    float v = fmaxf(acc[mt][nt][rr] + bv, 0.f);
                    outb[((size_t)b*36864 + (size_t)yw*192 + xx)*128 + co] = bf16r(v);
                }
        }
    }
}

// ---------------- K9: out = x + (w3 @ h2b) + b3 via MFMA, h2b bf16 NHWC ----------------
__global__ __launch_bounds__(256, 2) void k_conv1x1m(const ushort* __restrict__ h2b, const uint4* __restrict__ w3b,
                                                     const float* __restrict__ b3, const float* __restrict__ x,
                                                     float* __restrict__ out) {
    __shared__ ushort Hs[128*136];
    __shared__ ushort Ws3[128*136];
    int px0 = blockIdx.x * 128;
    int b = blockIdx.y;
    int tid = threadIdx.x;
    int wv = tid >> 6, l = tid & 63, quad = l >> 4, l15 = l & 15;

    {
        const uint4* hsrc = (const uint4*)(h2b + ((size_t)b*36864 + px0)*128);
#pragma unroll
        for (int k = 0; k < 8; ++k) {
            int idx = tid + 256*k;
            int row = idx >> 4, co8 = idx & 15;
            *(uint4*)&Hs[row*136 + co8*8] = hsrc[idx];
            *(uint4*)&Ws3[row*136 + co8*8] = w3b[idx];
        }
    }
    __syncthreads();

    floatx4 oacc[2][8];
#pragma unroll
    for (int mt = 0; mt < 2; ++mt)
#pragma unroll
        for (int nt = 0; nt < 8; ++nt) oacc[mt][nt] = (floatx4){0.f,0.f,0.f,0.f};

#pragma unroll
    for (int kk = 0; kk < 4; ++kk) {
        const short8 aq0 = *(const short8*)&Hs[(wv*32 + l15)*136 + kk*32 + quad*8];
        const short8 aq1 = *(const short8*)&Hs[(wv*32 + 16 + l15)*136 + kk*32 + quad*8];
#pragma unroll
        for (int nt = 0; nt < 8; ++nt) {
            const short8 bw = *(const short8*)&Ws3[(nt*16 + l15)*136 + kk*32 + quad*8];
            oacc[0][nt] = __builtin_amdgcn_mfma_f32_16x16x32_bf16(aq0, bw, oacc[0][nt], 0, 0, 0);
            oacc[1][nt] = __builtin_amdgcn_mfma_f32_16x16x32_bf16(aq1, bw, oacc[1][nt], 0, 0, 0);
        }
    }

#pragma unroll
    for (int nt = 0; nt < 8; ++nt) {
        int co = nt*16 + l15;
        float bv = b3[co];
        size_t pbase = ((size_t)b*128 + co)*HW + px0 + wv*32 + quad*4;
#pragma unroll
        for (int mt = 0; mt < 2; ++mt) {
            const float4 xv = *(const float4*)&x[pbase + mt*16];
            float4 o;
            o.x = oacc[mt][nt][0] + bv + xv.x;
            o.y = oacc[mt][nt][1] + bv + xv.y;
            o.z = oacc[mt][nt][2] + bv + xv.z;
            o.w = oacc[mt][nt][3] + bv + xv.w;
            *(float4*)&out[pbase + mt*16] = o;
        }
    }
}

extern "C" void kernel_launch(void* const* d_in, const int* in_sizes, int n_in,
                              void* d_out, int out_size, void* d_ws, size_t ws_size,
                              hipStream_t stream) {
    (void)in_sizes; (void)n_in; (void)out_size; (void)ws_size;
    const float* x   = (const float*)d_in[0];
    const float* wqk = (const float*)d_in[1];
    const float* w1  = (const float*)d_in[2];
    const float* b1  = (const float*)d_in[3];
    const float* w2  = (const float*)d_in[4];
    const float* b2  = (const float*)d_in[5];
    const float* w3  = (const float*)d_in[6];
    const float* b3  = (const float*)d_in[7];
    float* out = (float*)d_out;
    char* ws = (char*)d_ws;
    float* stats = (float*)ws;
    const size_t SZ = (size_t)BF * NN * CCH * sizeof(float);   // 37,748,736 B
    char* Abase = ws + 256;
    char* Bbase = ws + 256 + SZ;
    char* Cbase = ws + 256 + 2*SZ;
    ushort* Vt  = (ushort*)Abase;
    ushort* Xnb = (ushort*)Bbase;      // bf16
    ushort* qkn = (ushort*)Cbase;
    float*  O   = (float*)Bbase;
    uint4*  yb  = (uint4*)Cbase;
    uint4*  h1b = (uint4*)Abase;
    ushort* h2b = (ushort*)Bbase;      // bf16 NHWC flat, 18.9 MB
    uint4* wb1   = (uint4*)(Abase + 20*1024*1024);
    uint4* wb2   = (uint4*)(Abase + 21*1024*1024);
    uint4* w3b   = (uint4*)(Abase + 22*1024*1024);
    uint4* wqkTb = (uint4*)(Abase + 23*1024*1024);

    hipMemsetAsync(stats, 0, 4*sizeof(float), stream);
    k_reduce     <<<dim3(288, 2),     256, 0, stream>>>(x, stats);
    k_finalize   <<<1, 64,            0, stream>>>(stats);
    k_cast_w     <<<dim3(72, 3),      256, 0, stream>>>(w1, w2, w3, wqk, wb1, wb2, w3b, wqkTb);
    k_unshuffle  <<<dim3(3, 192, 2),  256, 0, stream>>>(x, stats, Vt, Xnb);
    k_qk         <<<1152,             256, 0, stream>>>(Xnb, (const ushort*)wqkTb, qkn);
    k_attn       <<<384,              256, 0, stream>>>(qkn, Vt, O);
    k_shuffle_add<<<dim3(3, 192, 2),  256, 0, stream>>>(O, x, yb);
    k_conv3m     <<<dim3(6, 48, 2),   256, 0, stream>>>(yb,  wb1, b1, (void*)h1b, 0);
    k_conv3m     <<<dim3(6, 48, 2),   256, 0, stream>>>(h1b, wb2, b2, (void*)h2b, 1);
    k_conv1x1m   <<<dim3(288, 2),     256, 0, stream>>>(h2b, w3b, b3, x, out);
}